// Round 12
// baseline (112.301 us; speedup 1.0000x reference)
//
#include <hip/hip_runtime.h>

// Round 11: R10 theory with staging bug FIXED (each thread stages 8 short8s:
// full coverage of K[256][32] + V[32][256] per buffer). Attention KV tile 256,
// double-buffered (74.8 KB LDS), 8 iters, 80 MFMA/wave-iter.
// cvt/qkv/out = R8-passing versions, unchanged.

#define SEQ 2048
#define BATCH 4
#define NHEADS 8
#define HDIM 32
#define DIMC 256
#define SCALE_LOG2E 0.09016844005556021f  // (1/16)*log2(e)

typedef __attribute__((ext_vector_type(8))) short short8;
typedef __attribute__((ext_vector_type(4))) float f32x4;

union BF8 { unsigned u[4]; short8 s8; };

__device__ __forceinline__ unsigned pk2bf(float a, float b) {
    union { float f; unsigned u; } ua, ub;
    ua.f = a; ub.f = b;
    return __builtin_amdgcn_perm(ub.u + 0x8000u, ua.u + 0x8000u, 0x07060302u);
}
__device__ __forceinline__ short f2bf(float a) {
    union { float f; unsigned u; } x; x.f = a;
    return (short)((x.u + 0x8000u) >> 16);
}

#define NX (BATCH * SEQ * DIMC)
#define NQW (3 * DIMC * DIMC)
#define NOW (DIMC * DIMC)

__global__ __launch_bounds__(256) void cvt_bf16(const float* __restrict__ x,
                                                const float* __restrict__ wq,
                                                const float* __restrict__ wo,
                                                short* __restrict__ xb,
                                                short* __restrict__ wqb,
                                                short* __restrict__ wob) {
    int i = (blockIdx.x * 256 + threadIdx.x) * 4;
    const float* src;
    short* dst;
    int off;
    if (i < NX) { src = x; dst = xb; off = i; }
    else if (i < NX + NQW) { src = wq; dst = wqb; off = i - NX; }
    else { src = wo; dst = wob; off = i - NX - NQW; }
    float4 v = *(const float4*)&src[off];
    uint2 p;
    p.x = pk2bf(v.x, v.y);
    p.y = pk2bf(v.z, v.w);
    *(uint2*)&dst[off] = p;
}

// ---------------------------------------------------------------------------
// QKV GEMM (R7/R8): 128x64 tile, 768 blocks, software-pipelined staging.
// ---------------------------------------------------------------------------
__global__ __launch_bounds__(256) void qkv_mfma(const short* __restrict__ Xb,
                                                const short* __restrict__ Wb,
                                                const float* __restrict__ bias,
                                                short* __restrict__ Q,
                                                short* __restrict__ Kd,
                                                short* __restrict__ V) {
    __shared__ __align__(16) union SM {
        struct { short A[128][72]; short B[64][72]; } ab;
        short CQ[128][72];
        short CV[64][136];
    } sm;

    const int m0 = blockIdx.y * 128, bx = blockIdx.x;
    const int n0 = bx * 64;
    const int tid = threadIdx.x;
    const int w = tid >> 6, lane = tid & 63;
    const int m = lane & 15, g = lane >> 4;
    const int wr = w >> 1, wc = w & 1;

    const int arow = tid >> 1, acol = (tid & 1) * 32;
    const int brow = tid >> 2, bcol = (tid & 3) * 16;

    f32x4 acc[4][2] = {};

    const short* ap = Xb + (size_t)(m0 + arow) * DIMC + acol;
    const short* bp = Wb + (size_t)(n0 + brow) * DIMC + bcol;

    short8 pa[4], pb[2];
#pragma unroll
    for (int i = 0; i < 4; i++) pa[i] = *(const short8*)(ap + i * 8);
#pragma unroll
    for (int i = 0; i < 2; i++) pb[i] = *(const short8*)(bp + i * 8);

    for (int kt = 0; kt < DIMC; kt += 64) {
        __syncthreads();
#pragma unroll
        for (int i = 0; i < 4; i++) *(short8*)&sm.ab.A[arow][acol + i * 8] = pa[i];
#pragma unroll
        for (int i = 0; i < 2; i++) *(short8*)&sm.ab.B[brow][bcol + i * 8] = pb[i];
        __syncthreads();
        if (kt + 64 < DIMC) {
#pragma unroll
            for (int i = 0; i < 4; i++) pa[i] = *(const short8*)(ap + kt + 64 + i * 8);
#pragma unroll
            for (int i = 0; i < 2; i++) pb[i] = *(const short8*)(bp + kt + 64 + i * 8);
        }
#pragma unroll
        for (int kk = 0; kk < 2; kk++) {
            short8 af[4], bf[2];
#pragma unroll
            for (int mt = 0; mt < 4; mt++)
                af[mt] = *(const short8*)&sm.ab.A[wr * 64 + mt * 16 + m][kk * 32 + g * 8];
#pragma unroll
            for (int nt = 0; nt < 2; nt++)
                bf[nt] = *(const short8*)&sm.ab.B[wc * 32 + nt * 16 + m][kk * 32 + g * 8];
#pragma unroll
            for (int mt = 0; mt < 4; mt++)
#pragma unroll
                for (int nt = 0; nt < 2; nt++)
                    acc[mt][nt] = __builtin_amdgcn_mfma_f32_16x16x32_bf16(af[mt], bf[nt], acc[mt][nt], 0, 0, 0);
        }
    }

    const int which = bx >> 2;
    const int h0 = (bx & 3) * 2;
    const int bidx = blockIdx.y >> 4;
    const int ntok0 = (blockIdx.y & 15) * 128;
    float bv[2];
#pragma unroll
    for (int nt = 0; nt < 2; nt++) bv[nt] = bias[n0 + wc * 32 + nt * 16 + m];

    __syncthreads();
    if (which != 2) {
        const float qs = (which == 0) ? SCALE_LOG2E : 1.0f;
#pragma unroll
        for (int mt = 0; mt < 4; mt++)
#pragma unroll
            for (int nt = 0; nt < 2; nt++)
#pragma unroll
                for (int r = 0; r < 4; r++)
                    sm.CQ[wr * 64 + mt * 16 + g * 4 + r][wc * 32 + nt * 16 + m] =
                        f2bf((acc[mt][nt][r] + bv[nt]) * qs);
        __syncthreads();
        short* dst = (which == 0) ? Q : Kd;
        const int tok = tid >> 1, d0 = (tid & 1) * 16;
#pragma unroll
        for (int hh = 0; hh < 2; hh++) {
            size_t o = ((size_t)((bidx * NHEADS + h0 + hh) * SEQ) + ntok0 + tok) * HDIM + d0;
            *(short8*)&dst[o] = *(const short8*)&sm.CQ[tok][hh * 32 + d0];
            *(short8*)&dst[o + 8] = *(const short8*)&sm.CQ[tok][hh * 32 + d0 + 8];
        }
    } else {
#pragma unroll
        for (int mt = 0; mt < 4; mt++)
#pragma unroll
            for (int nt = 0; nt < 2; nt++) {
                uint2 p;
                p.x = pk2bf(acc[mt][nt][0] + bv[nt], acc[mt][nt][1] + bv[nt]);
                p.y = pk2bf(acc[mt][nt][2] + bv[nt], acc[mt][nt][3] + bv[nt]);
                *(uint2*)&sm.CV[wc * 32 + nt * 16 + m][wr * 64 + mt * 16 + g * 4] = p;
            }
        __syncthreads();
        const int col = tid >> 2, t0 = (tid & 3) * 32;
        const int hh = col >> 5, d = col & 31;
        size_t o = ((size_t)((bidx * NHEADS + h0 + hh) * HDIM) + d) * SEQ + ntok0 + t0;
#pragma unroll
        for (int c2 = 0; c2 < 4; c2++)
            *(short8*)&V[o + c2 * 8] = *(const short8*)&sm.CV[col][t0 + c2 * 8];
    }
}

// ---------------------------------------------------------------------------
// Attention: 128 q-rows/block, KV tile 256, double-buffered LDS (74.8 KB),
// k split across 4 waves (64 each). sigma-permuted K staging (32-row-block
// local); register-local P; 80 MFMA/wave-iter; 8 iters. Full staging:
// 4 K-loads + 4 V-loads per thread per iter. grid(16,32)=512 blocks.
// ---------------------------------------------------------------------------
__global__ __launch_bounds__(256, 2) void attn_tile(const short* __restrict__ Q,
                                                    const short* __restrict__ K,
                                                    const short* __restrict__ V,  // [bh][d][tok]
                                                    short* __restrict__ Zb) {
    __shared__ __align__(16) union SM {
        struct { short Ks[2][256][40]; short Vs[2][32][264]; } kv;   // 74752 B
        struct { float O[4][64][36]; float L[4][64]; } ep;           // 37888 B
    } sm;

    const int bh = blockIdx.y;
    const int b = bh >> 3, h = bh & 7;
    const int q0 = blockIdx.x * 128;
    const short* qb = Q + (size_t)bh * SEQ * HDIM;
    const short* kb = K + (size_t)bh * SEQ * HDIM;
    const short* vb = V + (size_t)bh * HDIM * SEQ;
    const int tid = threadIdx.x;
    const int w = tid >> 6, lane = tid & 63;
    const int m = lane & 15, g = lane >> 4;

    short8 qfr[8];
#pragma unroll
    for (int qt = 0; qt < 8; qt++)
        qfr[qt] = *(const short8*)(qb + (size_t)(q0 + qt * 16 + m) * HDIM + g * 8);

    // K staging: rows krow and krow+128 (of 256), 16 cols each (2 short8).
    const int krow = tid >> 1, kcol = (tid & 1) * 16;
    const int rl = krow & 31;
    const int lrow = (krow & ~31) | (((rl >> 2) & 1) << 4) | ((rl >> 3) << 2) | (rl & 3);
    // V staging: 32 d-rows, 16 cols at vcol and vcol+128 (2 short8 each).
    const int vrow = tid >> 3, vcol = (tid & 7) * 16;

    f32x4 o[8][2] = {};
    f32x4 ol[8] = {};
    const short8 ones = {0x3F80, 0x3F80, 0x3F80, 0x3F80, 0x3F80, 0x3F80, 0x3F80, 0x3F80};

    short8 pk[4], pv[4];
    pk[0] = *(const short8*)(kb + (size_t)krow * HDIM + kcol);
    pk[1] = *(const short8*)(kb + (size_t)krow * HDIM + kcol + 8);
    pk[2] = *(const short8*)(kb + (size_t)(krow + 128) * HDIM + kcol);
    pk[3] = *(const short8*)(kb + (size_t)(krow + 128) * HDIM + kcol + 8);
    pv[0] = *(const short8*)(vb + (size_t)vrow * SEQ + vcol);
    pv[1] = *(const short8*)(vb + (size_t)vrow * SEQ + vcol + 8);
    pv[2] = *(const short8*)(vb + (size_t)vrow * SEQ + vcol + 128);
    pv[3] = *(const short8*)(vb + (size_t)vrow * SEQ + vcol + 136);
    *(short8*)&sm.kv.Ks[0][lrow][kcol] = pk[0];
    *(short8*)&sm.kv.Ks[0][lrow][kcol + 8] = pk[1];
    *(short8*)&sm.kv.Ks[0][lrow + 128][kcol] = pk[2];
    *(short8*)&sm.kv.Ks[0][lrow + 128][kcol + 8] = pk[3];
    *(short8*)&sm.kv.Vs[0][vrow][vcol] = pv[0];
    *(short8*)&sm.kv.Vs[0][vrow][vcol + 8] = pv[1];
    *(short8*)&sm.kv.Vs[0][vrow][vcol + 128] = pv[2];
    *(short8*)&sm.kv.Vs[0][vrow][vcol + 136] = pv[3];
    __syncthreads();

    for (int it = 0; it < SEQ / 256; ++it) {
        const int buf = it & 1;
        if (it < SEQ / 256 - 1) {
            const int kn = (it + 1) * 256;
            pk[0] = *(const short8*)(kb + (size_t)(kn + krow) * HDIM + kcol);
            pk[1] = *(const short8*)(kb + (size_t)(kn + krow) * HDIM + kcol + 8);
            pk[2] = *(const short8*)(kb + (size_t)(kn + krow + 128) * HDIM + kcol);
            pk[3] = *(const short8*)(kb + (size_t)(kn + krow + 128) * HDIM + kcol + 8);
            pv[0] = *(const short8*)(vb + (size_t)vrow * SEQ + kn + vcol);
            pv[1] = *(const short8*)(vb + (size_t)vrow * SEQ + kn + vcol + 8);
            pv[2] = *(const short8*)(vb + (size_t)vrow * SEQ + kn + vcol + 128);
            pv[3] = *(const short8*)(vb + (size_t)vrow * SEQ + kn + vcol + 136);
        }

        short8 kf[4], vf[4];
#pragma unroll
        for (int t = 0; t < 4; t++)
            kf[t] = *(const short8*)&sm.kv.Ks[buf][w * 64 + t * 16 + m][g * 8];
        vf[0] = *(const short8*)&sm.kv.Vs[buf][m][w * 64 + g * 8];
        vf[1] = *(const short8*)&sm.kv.Vs[buf][16 + m][w * 64 + g * 8];
        vf[2] = *(const short8*)&sm.kv.Vs[buf][m][w * 64 + 32 + g * 8];
        vf[3] = *(const short8*)&sm.kv.Vs[buf][16 + m][w * 64 + 32 + g * 8];

#pragma unroll
        for (int qt = 0; qt < 8; qt++) {
            f32x4 z4 = {0.f, 0.f, 0.f, 0.f};
            f32x4 st0 = __builtin_amdgcn_mfma_f32_16x16x32_bf16(kf[0], qfr[qt], z4, 0, 0, 0);
            f32x4 st1 = __builtin_amdgcn_mfma_f32_16x16x32_bf16(kf[1], qfr[qt], z4, 0, 0, 0);
            f32x4 st2 = __builtin_amdgcn_mfma_f32_16x16x32_bf16(kf[2], qfr[qt], z4, 0, 0, 0);
            f32x4 st3 = __builtin_amdgcn_mfma_f32_16x16x32_bf16(kf[3], qfr[qt], z4, 0, 0, 0);
            BF8 a0, a1;
            a0.u[0] = pk2bf(__builtin_amdgcn_exp2f(st0[0]), __builtin_amdgcn_exp2f(st0[1]));
            a0.u[1] = pk2bf(__builtin_amdgcn_exp2f(st0[2]), __builtin_amdgcn_exp2f(st0[3]));
            a0.u[2] = pk2bf(__builtin_amdgcn_exp2f(st1[0]), __builtin_amdgcn_exp2f(st1[1]));
            a0.u[3] = pk2bf(__builtin_amdgcn_exp2f(st1[2]), __builtin_amdgcn_exp2f(st1[3]));
            a1.u[0] = pk2bf(__builtin_amdgcn_exp2f(st2[0]), __builtin_amdgcn_exp2f(st2[1]));
            a1.u[1] = pk2bf(__builtin_amdgcn_exp2f(st2[2]), __builtin_amdgcn_exp2f(st2[3]));
            a1.u[2] = pk2bf(__builtin_amdgcn_exp2f(st3[0]), __builtin_amdgcn_exp2f(st3[1]));
            a1.u[3] = pk2bf(__builtin_amdgcn_exp2f(st3[2]), __builtin_amdgcn_exp2f(st3[3]));
            o[qt][0] = __builtin_amdgcn_mfma_f32_16x16x32_bf16(a0.s8, vf[0], o[qt][0], 0, 0, 0);
            o[qt][1] = __builtin_amdgcn_mfma_f32_16x16x32_bf16(a0.s8, vf[1], o[qt][1], 0, 0, 0);
            ol[qt] = __builtin_amdgcn_mfma_f32_16x16x32_bf16(a0.s8, ones, ol[qt], 0, 0, 0);
            o[qt][0] = __builtin_amdgcn_mfma_f32_16x16x32_bf16(a1.s8, vf[2], o[qt][0], 0, 0, 0);
            o[qt][1] = __builtin_amdgcn_mfma_f32_16x16x32_bf16(a1.s8, vf[3], o[qt][1], 0, 0, 0);
            ol[qt] = __builtin_amdgcn_mfma_f32_16x16x32_bf16(a1.s8, ones, ol[qt], 0, 0, 0);
        }

        if (it < SEQ / 256 - 1) {
            const int nb = buf ^ 1;
            *(short8*)&sm.kv.Ks[nb][lrow][kcol] = pk[0];
            *(short8*)&sm.kv.Ks[nb][lrow][kcol + 8] = pk[1];
            *(short8*)&sm.kv.Ks[nb][lrow + 128][kcol] = pk[2];
            *(short8*)&sm.kv.Ks[nb][lrow + 128][kcol + 8] = pk[3];
            *(short8*)&sm.kv.Vs[nb][vrow][vcol] = pv[0];
            *(short8*)&sm.kv.Vs[nb][vrow][vcol + 8] = pv[1];
            *(short8*)&sm.kv.Vs[nb][vrow][vcol + 128] = pv[2];
            *(short8*)&sm.kv.Vs[nb][vrow][vcol + 136] = pv[3];
        }
        __syncthreads();
    }

    // Two-phase cross-wave reduction (64 q-rows per phase).
#pragma unroll
    for (int ph = 0; ph < 2; ph++) {
        if (ph) __syncthreads();
#pragma unroll
        for (int qt = 0; qt < 4; qt++) {
            const int qq = ph * 4 + qt;
#pragma unroll
            for (int dh = 0; dh < 2; dh++)
#pragma unroll
                for (int r = 0; r < 4; r++)
                    sm.ep.O[w][qt * 16 + g * 4 + r][dh * 16 + m] = o[qq][dh][r];
            if (m == 0)
#pragma unroll
                for (int r = 0; r < 4; r++)
                    sm.ep.L[w][qt * 16 + g * 4 + r] = ol[qq][r];
        }
        __syncthreads();

        const int ql = tid >> 2, d0 = (tid & 3) * 8;
        float lt = sm.ep.L[0][ql] + sm.ep.L[1][ql] + sm.ep.L[2][ql] + sm.ep.L[3][ql];
        float inv = __builtin_amdgcn_rcpf(lt);
        float sv[8];
#pragma unroll
        for (int j = 0; j < 8; j++)
            sv[j] = sm.ep.O[0][ql][d0 + j] + sm.ep.O[1][ql][d0 + j] +
                    sm.ep.O[2][ql][d0 + j] + sm.ep.O[3][ql][d0 + j];
        BF8 pz;
#pragma unroll
        for (int j = 0; j < 4; j++)
            pz.u[j] = pk2bf(sv[2 * j] * inv, sv[2 * j + 1] * inv);
        *(short8*)&Zb[(size_t)(b * SEQ + q0 + ph * 64 + ql) * DIMC + h * HDIM + d0] = pz.s8;
    }
}

// ---------------------------------------------------------------------------
// Out GEMM (R7/R8): 64x64 tile, 512 blocks, software-pipelined staging.
// ---------------------------------------------------------------------------
__global__ __launch_bounds__(256) void out_mfma(const short* __restrict__ A,
                                                const short* __restrict__ Wb,
                                                const float* __restrict__ bias,
                                                float* __restrict__ C) {
    __shared__ __align__(16) short As[64][72];
    __shared__ __align__(16) short Bs[64][72];
    const int m0 = blockIdx.y * 64, n0 = blockIdx.x * 64;
    const int tid = threadIdx.x;
    const int w = tid >> 6, lane = tid & 63;
    const int m = lane & 15, g = lane >> 4;
    const int srow = tid >> 2, scol = (tid & 3) * 16;

    f32x4 acc[4] = {};

    const short* ap = A + (size_t)(m0 + srow) * DIMC + scol;
    const short* bp = Wb + (size_t)(n0 + srow) * DIMC + scol;

    short8 pa[2], pb[2];
#pragma unroll
    for (int i = 0; i < 2; i++) {
        pa[i] = *(const short8*)(ap + i * 8);
        pb[i] = *(const short8*)(bp + i * 8);
    }

    for (int kt = 0; kt < DIMC; kt += 64) {
        __syncthreads();
#pragma unroll
        for (int i = 0; i < 2; i++) {
            *(short8*)&As[srow][scol + i * 8] = pa[i];
            *(short8*)&Bs[srow][scol + i * 8] = pb[i];
        }
        __syncthreads();
        if (kt + 64 < DIMC) {
#pragma unroll
            for (int i = 0; i < 2; i++) {
                pa[i] = *(const short8*)(ap + kt + 64 + i * 8);
                pb[i] = *(const short8*)(bp + kt + 64 + i * 8);
            }
        }
#pragma unroll
        for (int kk = 0; kk < 2; kk++) {
            short8 af = *(const short8*)&As[w * 16 + m][kk * 32 + g * 8];
#pragma unroll
            for (int nt = 0; nt < 4; nt++) {
                short8 bf = *(const short8*)&Bs[nt * 16 + m][kk * 32 + g * 8];
                acc[nt] = __builtin_amdgcn_mfma_f32_16x16x32_bf16(af, bf, acc[nt], 0, 0, 0);
            }
        }
    }

    float bv[4];
#pragma unroll
    for (int nt = 0; nt < 4; nt++) bv[nt] = bias[n0 + nt * 16 + m];
#pragma unroll
    for (int nt = 0; nt < 4; nt++)
#pragma unroll
        for (int r = 0; r < 4; r++)
            C[(size_t)(m0 + w * 16 + g * 4 + r) * DIMC + n0 + nt * 16 + m] = acc[nt][r] + bv[nt];
}

extern "C" void kernel_launch(void* const* d_in, const int* in_sizes, int n_in,
                              void* d_out, int out_size, void* d_ws, size_t ws_size,
                              hipStream_t stream) {
    const float* x     = (const float*)d_in[0];
    const float* w_qkv = (const float*)d_in[1];
    const float* b_qkv = (const float*)d_in[2];
    const float* w_out = (const float*)d_in[3];
    const float* b_out = (const float*)d_in[4];
    float* out = (float*)d_out;

    const size_t HSZ = (size_t)BATCH * NHEADS * SEQ * HDIM;
    short* xb  = (short*)d_ws;
    short* wqb = xb + NX;
    short* wob = wqb + NQW;
    short* qw  = wob + NOW;
    short* kw  = qw + HSZ;
    short* vw  = kw + HSZ;
    short* zb  = vw + HSZ;

    cvt_bf16<<<(NX + NQW + NOW) / 1024, 256, 0, stream>>>(x, w_qkv, w_out, xb, wqb, wob);
    qkv_mfma<<<dim3(12, 64), 256, 0, stream>>>(xb, wqb, b_qkv, qw, kw, vw);
    attn_tile<<<dim3(16, 32), 256, 0, stream>>>(qw, kw, vw, zb);
    out_mfma<<<dim3(4, 128), 256, 0, stream>>>(zb, wob, b_out, out);
}